// Round 1
// baseline (2586.724 us; speedup 1.0000x reference)
//
#include <hip/hip_runtime.h>
#include <math.h>

// Sizes: B=512, L=32, D=128, DT=128, S=63
#define SS 63
#define NEGF (-3.4028234663852886e+38f)

// d_out layout (floats): hidden(512*128) | thin(512*63*256) | trans(512*63) | lp | ent
#define OUT_THIN   65536
#define OUT_TRANS  8323072
#define OUT_LP     8355328
#define OUT_ENT    8387584

__device__ __forceinline__ int pmod(int a, int m) { int r = a % m; return (r < 0) ? r + m : r; }
__device__ __forceinline__ float sigf(float x) { return 1.0f / (1.0f + expf(-x)); }

// One block = 4 batch rows (r = tid>>8), 256 threads per row, full 61-step scan in-block.
__global__ __launch_bounds__(1024, 1) void spinn_kernel(
    const int* __restrict__ messages,
    const float* __restrict__ embedding,
    const float* __restrict__ track_W,
    const float* __restrict__ track_b,
    const float* __restrict__ trans_W,
    const float* __restrict__ trans_b,
    const float* __restrict__ comp_W,
    const float* __restrict__ comp_b,
    const float* __restrict__ ln_g,
    const float* __restrict__ ln_b,
    float* __restrict__ out)
{
  __shared__ __align__(16) float hS[4][128];
  __shared__ __align__(16) float cS[4][128];
  __shared__ __align__(16) float xsS[4][512];     // [top(128)|s1(128)|s2(128)|h(128)]
  __shared__ __align__(16) float gS[4][2][512];   // gates, K-split partials
  __shared__ __align__(16) float compS[4][384];   // packed [ci|co|cg]
  __shared__ double redD[4][4];
  __shared__ float redF[4][2];
  __shared__ float redF2[4][2];
  __shared__ int qS[4][33];
  __shared__ int scalS[4][8];                     // 0:qi 1:bp 2:us 3:len 4:is_r

  const int tid = (int)threadIdx.x;
  const int r = tid >> 8;
  const int c = tid & 255;
  const int b = (int)blockIdx.x * 4 + r;
  float* const thin = out + OUT_THIN;

  // ---------------- prologue ----------------
  if (c < 128) { hS[r][c] = 0.0f; cS[r][c] = 0.0f; }
  if (c < 33) qS[r][c] = (c == 0) ? 0 : ((c == 1) ? 1 : -1);
  if (c < 64) {  // wave 0 of each row-group: find_length via ballot
    int zz = (c < 32) ? (messages[b * 32 + c] == 0) : 0;
    unsigned long long mk = __ballot(zz != 0);
    if (c == 0) {
      int len = mk ? __ffsll((unsigned long long)mk) : 32;
      scalS[r][0] = 1;        // qi
      scalS[r][1] = 2;        // bp
      scalS[r][2] = len - 2;  // us
      scalS[r][3] = len;
      scalS[r][4] = 0;
      #pragma unroll
      for (int s = 0; s < 2; ++s) {  // t=0,1 outputs
        int done = (s >= 2 * len - 1);
        out[OUT_TRANS + b * SS + s] = done ? 2.0f : 0.0f;
        out[OUT_LP + b * SS + s] = 0.0f;
        out[OUT_ENT + b * SS + s] = 0.0f;
      }
    }
  }
  // zero thin[2..62] each call (harness poisons once; mid-scan reads rely on zeros)
  for (int s = 2; s < SS; ++s) thin[((size_t)b * SS + s) * 256 + c] = 0.0f;

  // thin[0], thin[1] = LN(emb[msg[0/1]])
  #pragma unroll
  for (int s = 0; s < 2; ++s) {
    const int tok = messages[b * 32 + s];
    float v0 = 0.f, v1 = 0.f;
    if (c < 128) {
      v0 = embedding[(size_t)tok * 256 + c];
      v1 = embedding[(size_t)tok * 256 + 128 + c];
      float sm = v0 + v1;
      #pragma unroll
      for (int off = 32; off; off >>= 1) sm += __shfl_down(sm, off);
      if ((c & 63) == 0) redF[r][c >> 6] = sm;
    }
    __syncthreads();
    const float mu = (redF[r][0] + redF[r][1]) * (1.0f / 256.0f);
    if (c < 128) {
      float d0 = v0 - mu, d1 = v1 - mu;
      float sq = d0 * d0 + d1 * d1;
      #pragma unroll
      for (int off = 32; off; off >>= 1) sq += __shfl_down(sq, off);
      if ((c & 63) == 0) redF2[r][c >> 6] = sq;
    }
    __syncthreads();
    if (c < 128) {
      float var = (redF2[r][0] + redF2[r][1]) * (1.0f / 256.0f);
      float inv = 1.0f / sqrtf(var + 1e-5f);
      thin[((size_t)b * SS + s) * 256 + c] = (v0 - mu) * inv * ln_g[c] + ln_b[c];
      thin[((size_t)b * SS + s) * 256 + 128 + c] = (v1 - mu) * inv * ln_g[128 + c] + ln_b[128 + c];
    }
    __syncthreads();
  }

  // ---------------- scan ----------------
  for (int t = 2; t < SS; ++t) {
    // A: gather x = [top_buf, s1, s2, h]
    const int qi = scalS[r][0];
    const int bp = scalS[r][1];
    const int q_top = qS[r][pmod(qi, 33)];
    if (c < 128) {
      const int tokbp = messages[b * 32 + bp];
      const float* t1p = thin + ((size_t)b * SS + pmod(q_top, SS)) * 256;
      const float* t2p = thin + ((size_t)b * SS + pmod(q_top - 1, SS)) * 256;
      xsS[r][c]       = embedding[(size_t)tokbp * 256 + c];
      xsS[r][128 + c] = t1p[c];
      xsS[r][256 + c] = t2p[c];
      xsS[r][384 + c] = hS[r][c];
    }
    __syncthreads();

    // B: gates = x @ track_W + track_b   (each thread: 4 cols, half of K)
    {
      const int kh = c >> 7;           // uniform per wave
      const int c4 = (c & 127) * 4;
      float a0, a1, a2, a3;
      if (kh == 0) {
        const float4 bb = *(const float4*)&track_b[c4];
        a0 = bb.x; a1 = bb.y; a2 = bb.z; a3 = bb.w;
      } else { a0 = a1 = a2 = a3 = 0.f; }
      const float* wp = track_W + (size_t)(kh * 256) * 512 + c4;
      const float* xp = &xsS[r][kh * 256];
      #pragma unroll 2
      for (int k4 = 0; k4 < 64; ++k4) {
        const float4 xv = *(const float4*)&xp[k4 * 4];
        float4 w;
        w = *(const float4*)(wp + (size_t)(k4 * 4 + 0) * 512);
        a0 = fmaf(xv.x, w.x, a0); a1 = fmaf(xv.x, w.y, a1); a2 = fmaf(xv.x, w.z, a2); a3 = fmaf(xv.x, w.w, a3);
        w = *(const float4*)(wp + (size_t)(k4 * 4 + 1) * 512);
        a0 = fmaf(xv.y, w.x, a0); a1 = fmaf(xv.y, w.y, a1); a2 = fmaf(xv.y, w.z, a2); a3 = fmaf(xv.y, w.w, a3);
        w = *(const float4*)(wp + (size_t)(k4 * 4 + 2) * 512);
        a0 = fmaf(xv.z, w.x, a0); a1 = fmaf(xv.z, w.y, a1); a2 = fmaf(xv.z, w.z, a2); a3 = fmaf(xv.z, w.w, a3);
        w = *(const float4*)(wp + (size_t)(k4 * 4 + 3) * 512);
        a0 = fmaf(xv.w, w.x, a0); a1 = fmaf(xv.w, w.y, a1); a2 = fmaf(xv.w, w.z, a2); a3 = fmaf(xv.w, w.w, a3);
      }
      *(float4*)&gS[r][kh][c4] = make_float4(a0, a1, a2, a3);
    }
    __syncthreads();

    // C: LSTM update + logit partials (fp64 reduce)
    if (c < 128) {
      const float gi = gS[r][0][c]       + gS[r][1][c];
      const float gf = gS[r][0][128 + c] + gS[r][1][128 + c];
      const float go = gS[r][0][256 + c] + gS[r][1][256 + c];
      const float gg = gS[r][0][384 + c] + gS[r][1][384 + c];
      const float cv = sigf(gf) * cS[r][c] + sigf(gi) * tanhf(gg);
      cS[r][c] = cv;
      const float hv = sigf(go) * tanhf(cv);
      hS[r][c] = hv;
      double p0 = (double)hv * (double)trans_W[2 * c];
      double p1 = (double)hv * (double)trans_W[2 * c + 1];
      #pragma unroll
      for (int off = 32; off; off >>= 1) { p0 += __shfl_down(p0, off); p1 += __shfl_down(p1, off); }
      if ((c & 63) == 0) { redD[r][(c >> 6) * 2] = p0; redD[r][(c >> 6) * 2 + 1] = p1; }
    }
    __syncthreads();

    // D: comp = h @ comp_W[128:256, {ci,co,cg} cols] + bias  (st1=st2=0 in ref => only these 384 cols matter)
    if (c < 192) {
      const int p0i = 2 * c;
      const int col0 = (p0i < 128) ? p0i : (p0i + 256);  // packed->(0:128)=ci,(128:256)->384..=co,(256:384)->512..=cg
      const float2 bb = *(const float2*)&comp_b[col0];
      float a0 = bb.x, a1 = bb.y;
      const float* wp = comp_W + (size_t)128 * 640 + col0;
      #pragma unroll 2
      for (int k4 = 0; k4 < 32; ++k4) {
        const float4 hv = *(const float4*)&hS[r][k4 * 4];
        float2 w;
        w = *(const float2*)(wp + (size_t)(k4 * 4 + 0) * 640); a0 = fmaf(hv.x, w.x, a0); a1 = fmaf(hv.x, w.y, a1);
        w = *(const float2*)(wp + (size_t)(k4 * 4 + 1) * 640); a0 = fmaf(hv.y, w.x, a0); a1 = fmaf(hv.y, w.y, a1);
        w = *(const float2*)(wp + (size_t)(k4 * 4 + 2) * 640); a0 = fmaf(hv.z, w.x, a0); a1 = fmaf(hv.z, w.y, a1);
        w = *(const float2*)(wp + (size_t)(k4 * 4 + 3) * 640); a0 = fmaf(hv.w, w.x, a0); a1 = fmaf(hv.w, w.y, a1);
      }
      *(float2*)&compS[r][p0i] = make_float2(a0, a1);
    } else if (c == 192) {
      // per-row scalar: logits, mask, log_softmax, argmax, stack updates, outputs
      const int qi0 = scalS[r][0];
      const int bp0 = scalS[r][1];
      const int us  = scalS[r][2];
      const int len = scalS[r][3];
      float l0 = (float)(redD[r][0] + redD[r][2]) + trans_b[0];
      float l1 = (float)(redD[r][1] + redD[r][3]) + trans_b[1];
      if (us == 0)  l0 += NEGF;
      if (qi0 <= 0) l1 += NEGF;
      const int trans = (l1 > l0) ? 1 : 0;   // argmax, first-max on ties
      const float m = fmaxf(l0, l1);
      const float sh0 = l0 - m, sh1 = l1 - m;
      const float lse = logf(expf(sh0) + expf(sh1));
      const float lp0 = sh0 - lse, lp1 = sh1 - lse;
      const float logp = trans ? lp1 : lp0;
      const float pe0 = expf(lp0), pe1 = expf(lp1);
      const float ent = -((pe0 > 0.f ? pe0 * lp0 : 0.f) + (pe1 > 0.f ? pe1 * lp1 : 0.f));
      const int is_s = (trans == 0) ? 1 : 0;
      const int is_r = 1 - is_s;
      int qi2 = qi0 + is_s - is_r;
      qi2 = (qi2 < -1) ? -1 : ((qi2 > 31) ? 31 : qi2);
      int bp2 = bp0 + is_s; if (bp2 > 31) bp2 = 31;
      qS[r][pmod(qi2, 33)] = t;
      const int nxt = pmod(qi2 + 1, 33);
      if (is_r) qS[r][nxt] = -1;
      scalS[r][0] = qi2;
      scalS[r][1] = bp2;
      scalS[r][2] = us - is_s;
      scalS[r][4] = is_r;
      const int done = (t >= 2 * len - 1);
      out[OUT_TRANS + b * SS + t] = done ? 2.0f : (float)trans;
      out[OUT_LP + b * SS + t]    = done ? 0.0f : logp;
      out[OUT_ENT + b * SS + t]   = done ? 0.0f : ent;
    }
    __syncthreads();

    // E/F/G: new = is_r ? [ch,cc] : emb[msg[bp_new]];  thin[t] = LN(new)
    const int is_r = scalS[r][4];
    const int bpn  = scalS[r][1];
    float v0 = 0.f, v1 = 0.f;
    float* const thinRow = thin + ((size_t)b * SS + t) * 256;
    if (c < 128) {
      if (is_r) {
        const float ci = compS[r][c];
        const float co = compS[r][128 + c];
        const float cg = compS[r][256 + c];
        v1 = sigf(ci) * tanhf(cg);   // cc (s1c=s2c=0 in ref)
        v0 = sigf(co) * v1;          // ch
      } else {
        const int tok2 = messages[b * 32 + bpn];
        v0 = embedding[(size_t)tok2 * 256 + c];
        v1 = embedding[(size_t)tok2 * 256 + 128 + c];
      }
      float sm = v0 + v1;
      #pragma unroll
      for (int off = 32; off; off >>= 1) sm += __shfl_down(sm, off);
      if ((c & 63) == 0) redF[r][c >> 6] = sm;
    }
    __syncthreads();
    const float mu = (redF[r][0] + redF[r][1]) * (1.0f / 256.0f);
    if (c < 128) {
      const float d0 = v0 - mu, d1 = v1 - mu;
      float sq = d0 * d0 + d1 * d1;
      #pragma unroll
      for (int off = 32; off; off >>= 1) sq += __shfl_down(sq, off);
      if ((c & 63) == 0) redF2[r][c >> 6] = sq;
    }
    __syncthreads();
    if (c < 128) {
      const float var = (redF2[r][0] + redF2[r][1]) * (1.0f / 256.0f);
      const float inv = 1.0f / sqrtf(var + 1e-5f);
      thinRow[c]       = (v0 - mu) * inv * ln_g[c] + ln_b[c];
      thinRow[128 + c] = (v1 - mu) * inv * ln_g[128 + c] + ln_b[128 + c];
    }
    __syncthreads();
  }

  // epilogue: hidden = thin[2*len-2][:128]
  {
    const int len = scalS[r][3];
    if (c < 128) {
      out[(size_t)b * 128 + c] = thin[((size_t)b * SS + (2 * len - 2)) * 256 + c];
    }
  }
}

extern "C" void kernel_launch(void* const* d_in, const int* in_sizes, int n_in,
                              void* d_out, int out_size, void* d_ws, size_t ws_size,
                              hipStream_t stream) {
  const int*   messages  = (const int*)d_in[0];
  const float* embedding = (const float*)d_in[1];
  const float* track_W   = (const float*)d_in[2];
  const float* track_b   = (const float*)d_in[3];
  const float* trans_W   = (const float*)d_in[4];
  const float* trans_b   = (const float*)d_in[5];
  const float* comp_W    = (const float*)d_in[6];
  const float* comp_b    = (const float*)d_in[7];
  const float* ln_g      = (const float*)d_in[8];
  const float* ln_b      = (const float*)d_in[9];
  float* out = (float*)d_out;
  (void)in_sizes; (void)n_in; (void)out_size; (void)d_ws; (void)ws_size;

  spinn_kernel<<<dim3(128), dim3(1024), 0, stream>>>(
      messages, embedding, track_W, track_b, trans_W, trans_b,
      comp_W, comp_b, ln_g, ln_b, out);
}

// Round 2
// 857.338 us; speedup vs baseline: 3.0172x; 3.0172x over previous
//
#include <hip/hip_runtime.h>
#include <math.h>

// Sizes: B=512, L=32, D=128, DT=128, S=63
#define SS 63
#define NEGF (-3.4028234663852886e+38f)

// d_out layout (floats): hidden(512*128) | thin(512*63*256) | trans(512*63) | lp | ent
#define OUT_THIN   65536
#define OUT_TRANS  8323072
#define OUT_LP     8355328
#define OUT_ENT    8387584

__device__ __forceinline__ float sigf(float x) { return 1.0f / (1.0f + expf(-x)); }

#define FMA4(s, w, a) { a.x = fmaf(s, w.x, a.x); a.y = fmaf(s, w.y, a.y); \
                        a.z = fmaf(s, w.z, a.z); a.w = fmaf(s, w.w, a.w); }

// 256 blocks x 2 rows x 512 threads. Weights loaded ONCE per block per step,
// FMA'd into both rows' accumulators (register-level sharing).
// Key reference identities (verified round 1): s1 = thin[t-1], s2 = thin[t-2]
// always; compose's st1/st2 are always zero rows -> comp needs only the h-part
// (K rows 128..255) and only the ci/co/cg columns (384 of 640).
__global__ __launch_bounds__(512, 2) void spinn_kernel(
    const int* __restrict__ messages,
    const float* __restrict__ embedding,
    const float* __restrict__ track_W,
    const float* __restrict__ track_b,
    const float* __restrict__ trans_W,
    const float* __restrict__ trans_b,
    const float* __restrict__ comp_W,
    const float* __restrict__ comp_b,
    const float* __restrict__ ln_g,
    const float* __restrict__ ln_b,
    float* __restrict__ out)
{
  __shared__ __align__(16) float gS[2][4][512];     // track partials [row][kq][col]
  __shared__ __align__(16) float compS[2][4][384];  // comp partials [row][kq][packed ci|co|cg]
  __shared__ __align__(16) float thinL[2][2][128];  // rolling thin[t-1], thin[t-2] (first halves)
  __shared__ __align__(16) float topS[2][128];      // emb[msg[bp]] first half (= next top_buf)
  __shared__ __align__(16) float e1S[2][128];       // emb[msg[bp]] second half
  __shared__ __align__(16) float hS[2][128];
  __shared__ __align__(16) float cS[2][128];
  __shared__ float tbS[512];                        // track_b
  __shared__ float cbS[384];                        // comp_b packed [ci|co|cg]
  __shared__ float lgS[256], lbS[256];
  __shared__ float twS[256];                        // trans_W
  __shared__ float twbS[2];                         // trans_b
  __shared__ int   msgS[2][32];
  __shared__ int   scalS[2][8];                     // 0:qi 1:bp 2:us 3:len 4:is_r
  __shared__ double redS[2][2][2];                  // LN stats [row][wavehalf][sum,sumsq]
  __shared__ double redP[8][2];                     // prologue LN

  const int tid = (int)threadIdx.x;
  const int b0 = (int)blockIdx.x * 2;

  // ---------------- P0: stage constants ----------------
  if (tid < 64) msgS[tid >> 5][tid & 31] = messages[(b0 + (tid >> 5)) * 32 + (tid & 31)];
  if (tid < 2) twbS[tid] = trans_b[tid];
  tbS[tid] = track_b[tid];
  if (tid < 384) {
    const int g = tid >> 7;
    const int off = (g == 0) ? 0 : ((g == 1) ? 384 : 512);
    cbS[tid] = comp_b[off + (tid & 127)];
  }
  if (tid < 256) {
    lgS[tid] = ln_g[tid]; lbS[tid] = ln_b[tid]; twS[tid] = trans_W[tid];
    hS[tid >> 7][tid & 127] = 0.0f; cS[tid >> 7][tid & 127] = 0.0f;
  }
  __syncthreads();

  // ---------------- P1: scalar init + topS for t=2 ----------------
  if (tid < 2) {
    const int r = tid;
    int len = 32;
    for (int i = 0; i < 32; ++i) if (msgS[r][i] == 0) { len = i + 1; break; }
    scalS[r][0] = 1; scalS[r][1] = 2; scalS[r][2] = len - 2; scalS[r][3] = len; scalS[r][4] = 0;
    const int bb = b0 + r;
    #pragma unroll
    for (int s = 0; s < 2; ++s) {
      const int done = (s >= 2 * len - 1);
      out[OUT_TRANS + bb * SS + s] = done ? 2.0f : 0.0f;
      out[OUT_LP + bb * SS + s] = 0.0f;
      out[OUT_ENT + bb * SS + s] = 0.0f;
    }
  }
  if (tid < 256) topS[tid >> 7][tid & 127] = embedding[(size_t)msgS[tid >> 7][2] * 256 + (tid & 127)];
  __syncthreads();

  // ---------------- P2/P3: thin[0], thin[1] = LN(emb[msg[0/1]]) ----------------
  {
    const int s = tid >> 8, row = (tid >> 7) & 1, c = tid & 127;
    const int tok = msgS[row][s];
    const float v0 = embedding[(size_t)tok * 256 + c];
    const float v1 = embedding[(size_t)tok * 256 + 128 + c];
    double sm = (double)v0 + (double)v1;
    double sq = (double)v0 * v0 + (double)v1 * v1;
    #pragma unroll
    for (int off = 32; off; off >>= 1) { sm += __shfl_down(sm, off); sq += __shfl_down(sq, off); }
    if ((tid & 63) == 0) { redP[tid >> 6][0] = sm; redP[tid >> 6][1] = sq; }
    __syncthreads();
    const int wb = (tid >> 7) << 1;
    const double mu_d = (redP[wb][0] + redP[wb + 1][0]) * (1.0 / 256.0);
    const double ex2  = (redP[wb][1] + redP[wb + 1][1]) * (1.0 / 256.0);
    const float muf = (float)mu_d;
    const float inv = 1.0f / sqrtf((float)(ex2 - mu_d * mu_d) + 1e-5f);
    const float o0 = (v0 - muf) * inv * lgS[c] + lbS[c];
    const float o1 = (v1 - muf) * inv * lgS[128 + c] + lbS[128 + c];
    float* tp = out + OUT_THIN + ((size_t)(b0 + row) * SS + s) * 256;
    tp[c] = o0; tp[128 + c] = o1;
    thinL[row][s][c] = o0;
    __syncthreads();
  }

  // ---------------- scan: t = 2 .. 62 ----------------
  for (int t = 2; t < SS; ++t) {
    // B: gates partials. x segments by kq: 0=top_buf 1=thin[t-1] 2=thin[t-2] 3=h
    {
      const int col4 = (tid & 127) << 2;
      const int kq = tid >> 7;                 // uniform per pair of waves
      const float *xb0, *xb1;
      if (kq == 0)      { xb0 = topS[0];               xb1 = topS[1]; }
      else if (kq == 1) { xb0 = thinL[0][(t + 1) & 1]; xb1 = thinL[1][(t + 1) & 1]; }
      else if (kq == 2) { xb0 = thinL[0][t & 1];       xb1 = thinL[1][t & 1]; }
      else              { xb0 = hS[0];                 xb1 = hS[1]; }
      const float* wp = track_W + (size_t)(kq << 7) * 512 + col4;
      float4 a0 = {0.f, 0.f, 0.f, 0.f}, a1 = {0.f, 0.f, 0.f, 0.f};
      #pragma unroll 4
      for (int k4 = 0; k4 < 32; ++k4) {
        const float4 x0 = *(const float4*)&xb0[k4 << 2];
        const float4 x1 = *(const float4*)&xb1[k4 << 2];
        float4 w;
        w = *(const float4*)(wp + (size_t)(k4 * 4 + 0) * 512); FMA4(x0.x, w, a0); FMA4(x1.x, w, a1);
        w = *(const float4*)(wp + (size_t)(k4 * 4 + 1) * 512); FMA4(x0.y, w, a0); FMA4(x1.y, w, a1);
        w = *(const float4*)(wp + (size_t)(k4 * 4 + 2) * 512); FMA4(x0.z, w, a0); FMA4(x1.z, w, a1);
        w = *(const float4*)(wp + (size_t)(k4 * 4 + 3) * 512); FMA4(x0.w, w, a0); FMA4(x1.w, w, a1);
      }
      *(float4*)&gS[0][kq][col4] = a0;
      *(float4*)&gS[1][kq][col4] = a1;
    }
    __syncthreads();

    // C: LSTM + logits (one wave per row: 2 cells/lane) + inline scalar decision
    if (tid < 128) {
      const int row = tid >> 6, l = tid & 63;
      double p0 = 0.0, p1 = 0.0;
      #pragma unroll
      for (int j = 0; j < 2; ++j) {
        const int cell = l + j * 64;
        const float gi = tbS[cell]       + gS[row][0][cell]       + gS[row][1][cell]       + gS[row][2][cell]       + gS[row][3][cell];
        const float gf = tbS[128 + cell] + gS[row][0][128 + cell] + gS[row][1][128 + cell] + gS[row][2][128 + cell] + gS[row][3][128 + cell];
        const float go = tbS[256 + cell] + gS[row][0][256 + cell] + gS[row][1][256 + cell] + gS[row][2][256 + cell] + gS[row][3][256 + cell];
        const float gg = tbS[384 + cell] + gS[row][0][384 + cell] + gS[row][1][384 + cell] + gS[row][2][384 + cell] + gS[row][3][384 + cell];
        const float cv = sigf(gf) * cS[row][cell] + sigf(gi) * tanhf(gg);
        const float hv = sigf(go) * tanhf(cv);
        cS[row][cell] = cv; hS[row][cell] = hv;
        p0 += (double)hv * (double)twS[2 * cell];
        p1 += (double)hv * (double)twS[2 * cell + 1];
      }
      #pragma unroll
      for (int off = 32; off; off >>= 1) { p0 += __shfl_down(p0, off); p1 += __shfl_down(p1, off); }
      if (l == 0) {
        const int qi0 = scalS[row][0], bp0 = scalS[row][1], us = scalS[row][2], len = scalS[row][3];
        float l0 = (float)p0 + twbS[0];
        float l1 = (float)p1 + twbS[1];
        if (us == 0)  l0 += NEGF;
        if (qi0 <= 0) l1 += NEGF;
        const int trans = (l1 > l0) ? 1 : 0;
        const float m = fmaxf(l0, l1);
        const float sh0 = l0 - m, sh1 = l1 - m;
        const float lse = logf(expf(sh0) + expf(sh1));
        const float lp0 = sh0 - lse, lp1 = sh1 - lse;
        const float logp = trans ? lp1 : lp0;
        const float pe0 = expf(lp0), pe1 = expf(lp1);
        const float ent = -((pe0 > 0.f ? pe0 * lp0 : 0.f) + (pe1 > 0.f ? pe1 * lp1 : 0.f));
        const int is_s = trans ? 0 : 1;
        const int is_r = trans;
        int qi2 = qi0 + is_s - is_r; qi2 = (qi2 < -1) ? -1 : ((qi2 > 31) ? 31 : qi2);
        int bp2 = bp0 + is_s; if (bp2 > 31) bp2 = 31;
        scalS[row][0] = qi2; scalS[row][1] = bp2; scalS[row][2] = us - is_s; scalS[row][4] = is_r;
        const int bb = b0 + row;
        const int done = (t >= 2 * len - 1);
        out[OUT_TRANS + bb * SS + t] = done ? 2.0f : (float)trans;
        out[OUT_LP + bb * SS + t]    = done ? 0.0f : logp;
        out[OUT_ENT + bb * SS + t]   = done ? 0.0f : ent;
      }
    }
    __syncthreads();

    // D: embedding prefetch (tid<128) || comp matvec (tid>=128, skipped if no reduce)
    if (tid < 128) {
      const int row = tid >> 6, c2 = (tid & 63) << 1;
      const int tok = msgS[row][scalS[row][1]];
      const float2 ea = *(const float2*)&embedding[(size_t)tok * 256 + c2];
      const float2 eb = *(const float2*)&embedding[(size_t)tok * 256 + 128 + c2];
      *(float2*)&topS[row][c2] = ea;
      *(float2*)&e1S[row][c2] = eb;
    } else if (scalS[0][4] | scalS[1][4]) {
      const int u = tid - 128;
      const int g = u >> 7;                    // 0:ci 1:co 2:cg
      const int w7 = u & 127;
      const int col4 = (w7 & 31) << 2;
      const int kq = w7 >> 5;
      const int colbase = (g == 0) ? 0 : ((g == 1) ? 384 : 512);
      const float* wp = comp_W + (size_t)(128 + (kq << 5)) * 640 + colbase + col4;
      float4 a0 = {0.f, 0.f, 0.f, 0.f}, a1 = {0.f, 0.f, 0.f, 0.f};
      #pragma unroll 2
      for (int k4 = 0; k4 < 8; ++k4) {
        const float4 h0 = *(const float4*)&hS[0][(kq << 5) + (k4 << 2)];
        const float4 h1 = *(const float4*)&hS[1][(kq << 5) + (k4 << 2)];
        float4 w;
        w = *(const float4*)(wp + (size_t)(k4 * 4 + 0) * 640); FMA4(h0.x, w, a0); FMA4(h1.x, w, a1);
        w = *(const float4*)(wp + (size_t)(k4 * 4 + 1) * 640); FMA4(h0.y, w, a0); FMA4(h1.y, w, a1);
        w = *(const float4*)(wp + (size_t)(k4 * 4 + 2) * 640); FMA4(h0.z, w, a0); FMA4(h1.z, w, a1);
        w = *(const float4*)(wp + (size_t)(k4 * 4 + 3) * 640); FMA4(h0.w, w, a0); FMA4(h1.w, w, a1);
      }
      *(float4*)&compS[0][kq][(g << 7) + col4] = a0;
      *(float4*)&compS[1][kq][(g << 7) + col4] = a1;
    }
    __syncthreads();

    // E: compose/shift select + LN (single-pass fp64 stats), write thin
    float v0 = 0.f, v1 = 0.f;
    if (tid < 256) {
      const int row = tid >> 7, c = tid & 127;
      const float e0 = topS[row][c], e1v = e1S[row][c];
      if (scalS[row][4]) {
        const float ci = cbS[c]       + compS[row][0][c]       + compS[row][1][c]       + compS[row][2][c]       + compS[row][3][c];
        const float co = cbS[128 + c] + compS[row][0][128 + c] + compS[row][1][128 + c] + compS[row][2][128 + c] + compS[row][3][128 + c];
        const float cg = cbS[256 + c] + compS[row][0][256 + c] + compS[row][1][256 + c] + compS[row][2][256 + c] + compS[row][3][256 + c];
        v1 = sigf(ci) * tanhf(cg);   // cc
        v0 = sigf(co) * v1;          // ch
      } else { v0 = e0; v1 = e1v; }
      double sm = (double)v0 + (double)v1;
      double sq = (double)v0 * v0 + (double)v1 * v1;
      #pragma unroll
      for (int off = 32; off; off >>= 1) { sm += __shfl_down(sm, off); sq += __shfl_down(sq, off); }
      if ((tid & 63) == 0) { redS[row][(tid >> 6) & 1][0] = sm; redS[row][(tid >> 6) & 1][1] = sq; }
    }
    __syncthreads();
    if (tid < 256) {
      const int row = tid >> 7, c = tid & 127;
      const double mu_d = (redS[row][0][0] + redS[row][1][0]) * (1.0 / 256.0);
      const double ex2  = (redS[row][0][1] + redS[row][1][1]) * (1.0 / 256.0);
      const float muf = (float)mu_d;
      const float inv = 1.0f / sqrtf((float)(ex2 - mu_d * mu_d) + 1e-5f);
      const float o0 = (v0 - muf) * inv * lgS[c] + lbS[c];
      const float o1 = (v1 - muf) * inv * lgS[128 + c] + lbS[128 + c];
      float* tp = out + OUT_THIN + ((size_t)(b0 + row) * SS + t) * 256;
      tp[c] = o0; tp[128 + c] = o1;
      thinL[row][t & 1][c] = o0;
    }
    __syncthreads();
  }

  // epilogue: hidden = thin[2*len-2][:128]
  if (tid < 256) {
    const int row = tid >> 7, c = tid & 127;
    const int len = scalS[row][3];
    const int bb = b0 + row;
    out[(size_t)bb * 128 + c] = out[OUT_THIN + ((size_t)bb * SS + (2 * len - 2)) * 256 + c];
  }
}

extern "C" void kernel_launch(void* const* d_in, const int* in_sizes, int n_in,
                              void* d_out, int out_size, void* d_ws, size_t ws_size,
                              hipStream_t stream) {
  const int*   messages  = (const int*)d_in[0];
  const float* embedding = (const float*)d_in[1];
  const float* track_W   = (const float*)d_in[2];
  const float* track_b   = (const float*)d_in[3];
  const float* trans_W   = (const float*)d_in[4];
  const float* trans_b   = (const float*)d_in[5];
  const float* comp_W    = (const float*)d_in[6];
  const float* comp_b    = (const float*)d_in[7];
  const float* ln_g      = (const float*)d_in[8];
  const float* ln_b      = (const float*)d_in[9];
  float* out = (float*)d_out;
  (void)in_sizes; (void)n_in; (void)out_size; (void)d_ws; (void)ws_size;

  spinn_kernel<<<dim3(256), dim3(512), 0, stream>>>(
      messages, embedding, track_W, track_b, trans_W, trans_b,
      comp_W, comp_b, ln_g, ln_b, out);
}